// Round 16
// baseline (263.832 us; speedup 1.0000x reference)
//
#include <hip/hip_runtime.h>
#include <hip/hip_bf16.h>

#define B_SZ 32
#define N_SZ 2048
#define H_SZ 1024

typedef float f32x4 __attribute__((ext_vector_type(4)));
typedef short bf16x8 __attribute__((ext_vector_type(8)));

static __device__ __forceinline__ unsigned short f2bf(float f) {
    union { float f; unsigned u; } x; x.f = f;
    unsigned r = x.u + 0x7FFF + ((x.u >> 16) & 1);
    return (unsigned short)(r >> 16);
}

// fast tanh: (e^{2x}-1)/(e^{2x}+1), clamped so e never overflows
static __device__ __forceinline__ float fast_tanh(float x) {
    x = fminf(fmaxf(x, -15.f), 15.f);
    float e = __expf(2.f * x);
    return (e - 1.f) / (e + 1.f);
}

// ---------------- kernel 1: pack Wv f32 -> bf16 in wave-fragment order ----------------
// packed element index: ((((w*32 + k)*4 + t)*64) + lane)*8 + j
//   maps to Wv[g][h], g = w*64 + 16t + (lane&15), h = k*32 + (lane>>4)*8 + j
__global__ __launch_bounds__(256) void pack_wv_kernel(const float* __restrict__ wv,
                                                      short* __restrict__ out) {
    int o8 = blockIdx.x * 256 + threadIdx.x;      // 131072 threads, 8 elems each
    int lane = o8 & 63;
    int t    = (o8 >> 6) & 3;
    int k    = (o8 >> 8) & 31;
    int w    = (o8 >> 13) & 15;
    int g  = w * 64 + 16 * t + (lane & 15);
    int h0 = k * 32 + (lane >> 4) * 8;
    const float* src = wv + (size_t)g * 1024 + h0;
    float4 v0 = *(const float4*)(src);
    float4 v1 = *(const float4*)(src + 4);
    short4 s0, s1;
    s0.x = (short)f2bf(v0.x); s0.y = (short)f2bf(v0.y);
    s0.z = (short)f2bf(v0.z); s0.w = (short)f2bf(v0.w);
    s1.x = (short)f2bf(v1.x); s1.y = (short)f2bf(v1.y);
    s1.z = (short)f2bf(v1.z); s1.w = (short)f2bf(v1.w);
    *(short4*)(out + (size_t)o8 * 8)     = s0;
    *(short4*)(out + (size_t)o8 * 8 + 4) = s1;
}

// ---------------- kernel 2: q_hid = query @ Wq.T + bias ----------------
__global__ __launch_bounds__(256) void qhid_kernel(const float* __restrict__ query,
                                                   const float* __restrict__ Wq,
                                                   const float* __restrict__ bias,
                                                   float* __restrict__ qh) {
    int gb = blockIdx.x * 4;
    __shared__ float wsm[4][1024];
    int t = threadIdx.x;
    for (int i = t; i < 4096; i += 256)
        wsm[i >> 10][i & 1023] = Wq[(size_t)gb * 1024 + i];
    __syncthreads();
    int gi = t >> 6;
    int lane = t & 63;
    int b = lane >> 1;
    int half = lane & 1;
    const float4* q = (const float4*)(query + b * 1024 + half * 512);
    const float4* w = (const float4*)(&wsm[gi][half * 512]);
    float acc = 0.f;
#pragma unroll 8
    for (int h = 0; h < 128; ++h) {
        float4 qv = q[h]; float4 wv = w[h];
        acc += qv.x * wv.x + qv.y * wv.y + qv.z * wv.z + qv.w * wv.w;
    }
    acc += __shfl_xor(acc, 1);
    if (half == 0) qh[b * 1024 + gb + gi] = acc + bias[gb + gi];
}

// ---------------- kernel 3: persistent-block fused score GEMM ----------------
// 256 blocks (1/CU), 512 threads (8 waves, 2 waves/SIMD, 256-reg budget).
// Each block owns 4 panels x 2 g-halves = 8 jobs; job = 64 rows x 512 g,
// K=1024 in 2 chunks of KC=512 (64KB LDS each, double-buffered, 128KB total).
// T14 pipeline: staging for chunk q+1 (f32 loads issued early, cvt+ds_write
// late) runs UNDER chunk q's 16 k-steps; one barrier per chunk. Both g-halves
// of a panel run back-to-back so the 2nd A-read hits L2/L3. Only the first
// chunk per block is unoverlapped. K-loop body/swizzle/epilogue = r15's.
__global__ __launch_bounds__(512, 2) void fused_score_kernel(
    const float* __restrict__ value, const float* __restrict__ cov,
    const short* __restrict__ wv_pk, const float* __restrict__ qh,
    const float* __restrict__ Wc, const float* __restrict__ Wm,
    float* __restrict__ e_part)
{
    extern __shared__ char smem[];                 // 2 x 64KB A-chunk + e_sm
    float* e_sm = (float*)(smem + 131072);

    const int bid = blockIdx.x;                    // 0..255
    const int tid = threadIdx.x;

    if (tid < 64) e_sm[tid] = 0.f;

    const int wave = tid >> 6;
    const int lane = tid & 63;
    const int lrow = lane & 15;
    const int lgrp = lane >> 4;
    const unsigned xorm = (unsigned)((lrow & 7) << 4);
    // chunk-local swizzled bases (row stride 1024B), ks-parity split (carry-safe)
    const unsigned base_e = ((unsigned)(lrow * 1024 + lgrp * 16)) ^ xorm;
    const unsigned base_o = ((unsigned)(lrow * 1024 + 64 + lgrp * 16)) ^ xorm;

    // staging role: lanes 0-7 share a row (8x f32x8 segments per row-chunk)
    const int srow  = tid >> 3;                    // 0..63
    const int scol8 = tid & 7;                     // 0..7
    const unsigned wbyte0 = (unsigned)(srow * 1024 + scol8 * 16);
    const unsigned wswz   = (unsigned)((srow & 7) << 4);

    // source base for linear chunk q (0..15): job j=q>>1, c=q&1
    auto src_base = [&](int q) -> const float* {
        int j = q >> 1, c = q & 1;
        int p = bid * 4 + (j >> 1);
        int b = p >> 5, n0 = (p & 31) * 64;
        return value + ((size_t)(b * N_SZ + n0) + srow) * H_SZ + c * 512 + scol8 * 8;
    };

// issue group g (its 2g, 2g+1): 4 float4 loads
#define ISSUE(S, SRC, g)                                                       \
    S[0] = *(const float4*)((SRC) + (2*(g))   * 64);                           \
    S[1] = *(const float4*)((SRC) + (2*(g))   * 64 + 4);                       \
    S[2] = *(const float4*)((SRC) + (2*(g)+1) * 64);                           \
    S[3] = *(const float4*)((SRC) + (2*(g)+1) * 64 + 4);
// convert + write group g into buffer at byte base BUF
#define WRITEG(S, g, BUF)                                                      \
    {   bf16x8 w0, w1;                                                         \
        w0[0]=(short)f2bf(S[0].x); w0[1]=(short)f2bf(S[0].y);                  \
        w0[2]=(short)f2bf(S[0].z); w0[3]=(short)f2bf(S[0].w);                  \
        w0[4]=(short)f2bf(S[1].x); w0[5]=(short)f2bf(S[1].y);                  \
        w0[6]=(short)f2bf(S[1].z); w0[7]=(short)f2bf(S[1].w);                  \
        w1[0]=(short)f2bf(S[2].x); w1[1]=(short)f2bf(S[2].y);                  \
        w1[2]=(short)f2bf(S[2].z); w1[3]=(short)f2bf(S[2].w);                  \
        w1[4]=(short)f2bf(S[3].x); w1[5]=(short)f2bf(S[3].y);                  \
        w1[6]=(short)f2bf(S[3].z); w1[7]=(short)f2bf(S[3].w);                  \
        *(bf16x8*)(smem + (BUF) + ((wbyte0 + (unsigned)((2*(g))*128)) ^ wswz)) = w0; \
        *(bf16x8*)(smem + (BUF) + ((wbyte0 + (unsigned)((2*(g)+1)*128)) ^ wswz)) = w1; }
// one k-step: prefetch next B, ds_read A, 16 MFMA
#define KSTEP(KF, KS, CUR)                                                     \
    {   bf16x8 bn[4];                                                          \
        const int kn_ = ((KF) + 1) & 31;                                       \
        _Pragma("unroll")                                                      \
        for (int t = 0; t < 4; ++t)                                            \
            bn[t] = *(const bf16x8*)(bbase + kn_ * 2048 + t * 512);            \
        bf16x8 afr[4];                                                         \
        const unsigned P_ = (((KS) & 1) ? base_o : base_e) + (CUR)             \
                          + (unsigned)(((KS) >> 1) * 128);                     \
        _Pragma("unroll")                                                      \
        for (int r = 0; r < 4; ++r)                                            \
            afr[r] = *(const bf16x8*)(smem + P_ + (unsigned)(r * 16384));      \
        _Pragma("unroll")                                                      \
        for (int r = 0; r < 4; ++r)                                            \
            _Pragma("unroll")                                                  \
            for (int t = 0; t < 4; ++t)                                        \
                acc[r][t] = __builtin_amdgcn_mfma_f32_16x16x32_bf16(           \
                    afr[r], bc[t], acc[r][t], 0, 0, 0);                        \
        _Pragma("unroll")                                                      \
        for (int t = 0; t < 4; ++t) bc[t] = bn[t];                             \
    }

    // ---- prologue: stage chunk 0 synchronously into buffer 0 ----
    {
        const float* s = src_base(0);
        float4 t0[4], t1[4], t2[4], t3[4];
        ISSUE(t0, s, 0) ISSUE(t1, s, 1) ISSUE(t2, s, 2) ISSUE(t3, s, 3)
        WRITEG(t0, 0, 0u) WRITEG(t1, 1, 0u) WRITEG(t2, 2, 0u) WRITEG(t3, 3, 0u)
    }
    __syncthreads();

    f32x4 acc[4][4];
#pragma unroll
    for (int r = 0; r < 4; ++r)
#pragma unroll
        for (int t = 0; t < 4; ++t) acc[r][t] = (f32x4){0.f, 0.f, 0.f, 0.f};

#pragma unroll 1
    for (int j = 0; j < 8; ++j) {
        const int p     = bid * 4 + (j >> 1);
        const int b     = p >> 5;
        const int n0    = (p & 31) * 64;
        const int ghalf = j & 1;
        const int wslot = ghalf * 8 + wave;
        const short* bbase = wv_pk + (size_t)wslot * 65536 + lane * 8;

        bf16x8 bc[4];
#pragma unroll
        for (int t = 0; t < 4; ++t)
            bc[t] = *(const bf16x8*)(bbase + t * 512);

#pragma unroll 1
        for (int c = 0; c < 2; ++c) {
            const int q = j * 2 + c;
            const bool hasNext = (q < 15);
            const float* nsrc = hasNext ? src_base(q + 1) : value;
            const unsigned CUR = (unsigned)((q & 1) * 65536);
            const unsigned NXT = CUR ^ 65536u;
            const int kf0 = c * 16;

            float4 s0[4], s1[4], s2[4], s3[4];
            if (hasNext) { ISSUE(s0, nsrc, 0) }
            KSTEP(kf0 + 0, 0, CUR) KSTEP(kf0 + 1, 1, CUR)
            KSTEP(kf0 + 2, 2, CUR) KSTEP(kf0 + 3, 3, CUR)
            if (hasNext) { WRITEG(s0, 0, NXT) ISSUE(s1, nsrc, 1) }
            KSTEP(kf0 + 4, 4, CUR) KSTEP(kf0 + 5, 5, CUR)
            KSTEP(kf0 + 6, 6, CUR) KSTEP(kf0 + 7, 7, CUR)
            if (hasNext) { WRITEG(s1, 1, NXT) ISSUE(s2, nsrc, 2) }
            KSTEP(kf0 + 8, 8, CUR) KSTEP(kf0 + 9, 9, CUR)
            KSTEP(kf0 + 10, 10, CUR) KSTEP(kf0 + 11, 11, CUR)
            if (hasNext) { WRITEG(s2, 2, NXT) ISSUE(s3, nsrc, 3) }
            KSTEP(kf0 + 12, 12, CUR) KSTEP(kf0 + 13, 13, CUR)
            KSTEP(kf0 + 14, 14, CUR) KSTEP(kf0 + 15, 15, CUR)
            if (hasNext) { WRITEG(s3, 3, NXT) }
            __syncthreads();
        }

        // ---- epilogue for job j ----
        float cv[4][4];
#pragma unroll
        for (int r = 0; r < 4; ++r)
#pragma unroll
            for (int i = 0; i < 4; ++i)
                cv[r][i] = cov[b * N_SZ + n0 + 16 * r + lgrp * 4 + i];

        float s_part[4][4];
#pragma unroll
        for (int r = 0; r < 4; ++r)
#pragma unroll
            for (int i = 0; i < 4; ++i) s_part[r][i] = 0.f;

        const int gbase = ghalf * 512 + wave * 64;
#pragma unroll
        for (int t = 0; t < 4; ++t) {
            int g = gbase + 16 * t + lrow;
            float qv = qh[b * 1024 + g];
            float wc = Wc[g];
            float wm = Wm[g];
#pragma unroll
            for (int r = 0; r < 4; ++r)
#pragma unroll
                for (int i = 0; i < 4; ++i) {
                    float aval = acc[r][t][i] + qv + cv[r][i] * wc;
                    s_part[r][i] += fast_tanh(aval) * wm;
                }
        }

#pragma unroll
        for (int r = 0; r < 4; ++r)
#pragma unroll
            for (int i = 0; i < 4; ++i) {
                float s = s_part[r][i];
                s += __shfl_xor(s, 1);
                s += __shfl_xor(s, 2);
                s += __shfl_xor(s, 4);
                s += __shfl_xor(s, 8);
                if (lrow == 0) atomicAdd(&e_sm[16 * r + lgrp * 4 + i], s);
            }
        __syncthreads();
        if (tid < 64) {
            e_part[((size_t)ghalf * B_SZ + b) * N_SZ + n0 + tid] = e_sm[tid];
            e_sm[tid] = 0.f;
        }
        __syncthreads();

#pragma unroll
        for (int r = 0; r < 4; ++r)
#pragma unroll
            for (int t = 0; t < 4; ++t) acc[r][t] = (f32x4){0.f, 0.f, 0.f, 0.f};
    }
#undef ISSUE
#undef WRITEG
#undef KSTEP
}

// ---------------- kernel 4: mask + softmax over n (sums the two e-halves) ----------------
__global__ __launch_bounds__(256) void softmax_kernel(const float* __restrict__ e_part,
                                                      const int* __restrict__ mask,
                                                      const float* __restrict__ bm,
                                                      float* __restrict__ attn_out) {
    int b = blockIdx.x;
    int t = threadIdx.x;
    int wave = t >> 6, lane = t & 63;
    float bmv = bm[0];
    float vals[8];
    float mx = -1e30f;
#pragma unroll
    for (int j = 0; j < 8; ++j) {
        int n = t + 256 * j;
        float ev = e_part[(size_t)b * N_SZ + n]
                 + e_part[((size_t)B_SZ + b) * N_SZ + n] + bmv;
        if (mask[b * N_SZ + n] <= 0) ev = -1e9f;
        vals[j] = ev;
        mx = fmaxf(mx, ev);
    }
#pragma unroll
    for (int m = 1; m < 64; m <<= 1) mx = fmaxf(mx, __shfl_xor(mx, m));
    __shared__ float redmax[4], redsum[4];
    if (lane == 0) redmax[wave] = mx;
    __syncthreads();
    mx = fmaxf(fmaxf(redmax[0], redmax[1]), fmaxf(redmax[2], redmax[3]));
    float sum = 0.f;
#pragma unroll
    for (int j = 0; j < 8; ++j) {
        vals[j] = expf(vals[j] - mx);
        sum += vals[j];
    }
#pragma unroll
    for (int m = 1; m < 64; m <<= 1) sum += __shfl_xor(sum, m);
    if (lane == 0) redsum[wave] = sum;
    __syncthreads();
    sum = redsum[0] + redsum[1] + redsum[2] + redsum[3];
    float inv = 1.f / sum;
#pragma unroll
    for (int j = 0; j < 8; ++j)
        attn_out[b * N_SZ + t + 256 * j] = vals[j] * inv;
}

// ---------------- kernel 5: partial weighted value sum (16 chunks/batch) ----------------
__global__ __launch_bounds__(256) void wsum_partial_kernel(const float* __restrict__ attn,
                                                           const float* __restrict__ value,
                                                           float* __restrict__ partial) {
    int b = blockIdx.x >> 4;
    int c = blockIdx.x & 15;
    int t = threadIdx.x;
    float4 acc = {0.f, 0.f, 0.f, 0.f};
    const float* vbase = value + (size_t)(b * N_SZ + c * 128) * H_SZ;
    const float* abase = attn + b * N_SZ + c * 128;
    for (int n = 0; n < 128; ++n) {
        float a = abase[n];
        if (a != 0.f) {
            float4 v = *(const float4*)(vbase + (size_t)n * H_SZ + t * 4);
            acc.x += a * v.x; acc.y += a * v.y;
            acc.z += a * v.z; acc.w += a * v.w;
        }
    }
    *(float4*)(partial + (size_t)blockIdx.x * H_SZ + t * 4) = acc;
}

// ---------------- kernel 6: reduce partials -> output ----------------
__global__ __launch_bounds__(256) void wsum_reduce_kernel(const float* __restrict__ partial,
                                                          float* __restrict__ out) {
    int i = blockIdx.x * 256 + threadIdx.x;   // 32768 total
    int b = i >> 10;
    int h = i & 1023;
    float s = 0.f;
#pragma unroll
    for (int c = 0; c < 16; ++c) s += partial[(size_t)(b * 16 + c) * H_SZ + h];
    out[i] = s;
}

extern "C" void kernel_launch(void* const* d_in, const int* in_sizes, int n_in,
                              void* d_out, int out_size, void* d_ws, size_t ws_size,
                              hipStream_t stream) {
    const float* query = (const float*)d_in[0];
    const float* value = (const float*)d_in[1];
    const int*   mask  = (const int*)  d_in[2];
    const float* cov   = (const float*)d_in[3];
    const float* Wq    = (const float*)d_in[4];
    const float* Wv    = (const float*)d_in[5];
    const float* Wc    = (const float*)d_in[6];
    const float* bias  = (const float*)d_in[7];
    const float* Wm    = (const float*)d_in[8];
    const float* bm    = (const float*)d_in[9];

    float* out      = (float*)d_out;            // [32*1024] output
    float* attn_out = out + B_SZ * H_SZ;        // [32*2048] attn

    char* ws = (char*)d_ws;
    short* wv_pk   = (short*)ws;                                       // 2 MB
    float* qh      = (float*)(ws + 2 * 1024 * 1024);                   // 128 KB
    float* e_part  = (float*)(ws + 2 * 1024 * 1024 + 128 * 1024);      // 512 KB (2 halves)
    float* partial = (float*)(ws + 2 * 1024 * 1024 + 640 * 1024);      // 2 MB

    pack_wv_kernel<<<512, 256, 0, stream>>>(Wv, wv_pk);
    qhid_kernel<<<256, 256, 0, stream>>>(query, Wq, bias, qh);

    size_t smem = 131072 + 256;
    fused_score_kernel<<<256, 512, smem, stream>>>(value, cov, wv_pk, qh, Wc, Wm, e_part);

    softmax_kernel<<<B_SZ, 256, 0, stream>>>(e_part, mask, bm, attn_out);
    wsum_partial_kernel<<<B_SZ * 16, 256, 0, stream>>>(attn_out, value, partial);
    wsum_reduce_kernel<<<128, 256, 0, stream>>>(partial, out);
}

// Round 17
// 228.464 us; speedup vs baseline: 1.1548x; 1.1548x over previous
//
#include <hip/hip_runtime.h>
#include <hip/hip_bf16.h>

#define B_SZ 32
#define N_SZ 2048
#define H_SZ 1024

typedef float f32x4 __attribute__((ext_vector_type(4)));
typedef short bf16x8 __attribute__((ext_vector_type(8)));

static __device__ __forceinline__ unsigned short f2bf(float f) {
    union { float f; unsigned u; } x; x.f = f;
    unsigned r = x.u + 0x7FFF + ((x.u >> 16) & 1);
    return (unsigned short)(r >> 16);
}

// fast tanh: (e^{2x}-1)/(e^{2x}+1), clamped so e never overflows
static __device__ __forceinline__ float fast_tanh(float x) {
    x = fminf(fmaxf(x, -15.f), 15.f);
    float e = __expf(2.f * x);
    return (e - 1.f) / (e + 1.f);
}

// ---------------- kernel 1: pack Wv f32 -> bf16 in wave-fragment order ----------------
// packed element index: ((((w*32 + k)*4 + t)*64) + lane)*8 + j
//   maps to Wv[g][h], g = w*64 + 16t + (lane&15), h = k*32 + (lane>>4)*8 + j
__global__ __launch_bounds__(256) void pack_wv_kernel(const float* __restrict__ wv,
                                                      short* __restrict__ out) {
    int o8 = blockIdx.x * 256 + threadIdx.x;      // 131072 threads, 8 elems each
    int lane = o8 & 63;
    int t    = (o8 >> 6) & 3;
    int k    = (o8 >> 8) & 31;
    int w    = (o8 >> 13) & 15;
    int g  = w * 64 + 16 * t + (lane & 15);
    int h0 = k * 32 + (lane >> 4) * 8;
    const float* src = wv + (size_t)g * 1024 + h0;
    float4 v0 = *(const float4*)(src);
    float4 v1 = *(const float4*)(src + 4);
    short4 s0, s1;
    s0.x = (short)f2bf(v0.x); s0.y = (short)f2bf(v0.y);
    s0.z = (short)f2bf(v0.z); s0.w = (short)f2bf(v0.w);
    s1.x = (short)f2bf(v1.x); s1.y = (short)f2bf(v1.y);
    s1.z = (short)f2bf(v1.z); s1.w = (short)f2bf(v1.w);
    *(short4*)(out + (size_t)o8 * 8)     = s0;
    *(short4*)(out + (size_t)o8 * 8 + 4) = s1;
}

// ---------------- kernel 2: q_hid = query @ Wq.T + bias ----------------
__global__ __launch_bounds__(256) void qhid_kernel(const float* __restrict__ query,
                                                   const float* __restrict__ Wq,
                                                   const float* __restrict__ bias,
                                                   float* __restrict__ qh) {
    int gb = blockIdx.x * 4;
    __shared__ float wsm[4][1024];
    int t = threadIdx.x;
    for (int i = t; i < 4096; i += 256)
        wsm[i >> 10][i & 1023] = Wq[(size_t)gb * 1024 + i];
    __syncthreads();
    int gi = t >> 6;
    int lane = t & 63;
    int b = lane >> 1;
    int half = lane & 1;
    const float4* q = (const float4*)(query + b * 1024 + half * 512);
    const float4* w = (const float4*)(&wsm[gi][half * 512]);
    float acc = 0.f;
#pragma unroll 8
    for (int h = 0; h < 128; ++h) {
        float4 qv = q[h]; float4 wv = w[h];
        acc += qv.x * wv.x + qv.y * wv.y + qv.z * wv.z + qv.w * wv.w;
    }
    acc += __shfl_xor(acc, 1);
    if (half == 0) qh[b * 1024 + gb + gi] = acc + bias[gb + gi];
}

// ---------------- kernel 3: fused score GEMM + tanh + Wm dot ----------------
// 512 threads (8 waves); block = one 64-row panel x one 512-g half.
// SIBLING PAIRING: p = ((wgid>>4)<<3)|(wgid&7), ghalf = (wgid>>3)&1
// -> sibling blocks (same panel, both g-halves) are 8 apart in blockIdx ->
// same XCD under round-robin -> panel's 2nd HBM read is an L2 hit
// (r15 verified: FETCH 184MB vs r8's 298MB with adjacent-bid pairing).
// LDS = 64KB A-tile (K chunked 2x512, single buffer) -> 2 blocks/CU,
// 4 waves/SIMD. Best-measured variant of 12 tried (228.2 us wall).
__global__ __launch_bounds__(512, 4) void fused_score_kernel(
    const float* __restrict__ value, const float* __restrict__ cov,
    const short* __restrict__ wv_pk, const float* __restrict__ qh,
    const float* __restrict__ Wc, const float* __restrict__ Wm,
    float* __restrict__ e_part)
{
    extern __shared__ char smem[];                 // 64KB A-chunk + e_sm
    float* e_sm = (float*)(smem + 65536);

    const int wgid  = blockIdx.x;
    const int p     = ((wgid >> 4) << 3) | (wgid & 7);   // panel 0..1023
    const int ghalf = (wgid >> 3) & 1;                   // which 512-g half
    const int b     = p >> 5;
    const int n0    = (p & 31) * 64;
    const int tid   = threadIdx.x;

    if (tid < 64) e_sm[tid] = 0.f;

    // staging role: lanes 0-7 share a row (128B contiguous global segments)
    const int srow  = tid >> 3;                    // 0..63
    const int scol8 = tid & 7;                     // 0..7 (8 f32 each)
    const float* gsrc = value + ((size_t)(b * N_SZ + n0) + srow) * H_SZ + scol8 * 8;
    const unsigned wswz = (unsigned)((srow & 7) << 4);
    const unsigned wbase = (unsigned)(srow * 1024 + scol8 * 16);

#define STAGE_CHUNK(CB)                                                        \
    {                                                                          \
        _Pragma("unroll")                                                      \
        for (int it = 0; it < 8; ++it) {                                       \
            float4 q0 = *(const float4*)(gsrc + (CB) + it * 64);               \
            float4 q1 = *(const float4*)(gsrc + (CB) + it * 64 + 4);           \
            bf16x8 w;                                                          \
            w[0] = (short)f2bf(q0.x); w[1] = (short)f2bf(q0.y);                \
            w[2] = (short)f2bf(q0.z); w[3] = (short)f2bf(q0.w);                \
            w[4] = (short)f2bf(q1.x); w[5] = (short)f2bf(q1.y);                \
            w[6] = (short)f2bf(q1.z); w[7] = (short)f2bf(q1.w);                \
            *(bf16x8*)(smem + ((wbase + (unsigned)(it * 128)) ^ wswz)) = w;    \
        }                                                                      \
    }

    // ---- stage chunk 0 (cols 0-511) ----
    STAGE_CHUNK(0)
    __syncthreads();

    const int wave = tid >> 6;
    const int lane = tid & 63;
    const int lrow = lane & 15;
    const int lgrp = lane >> 4;
    const unsigned xorm = (unsigned)((lrow & 7) << 4);
    // chunk-local swizzled bases (row stride 1024B), ks-parity split
    const unsigned base_e = ((unsigned)(lrow * 1024 + lgrp * 16)) ^ xorm;      // ks even
    const unsigned base_o = ((unsigned)(lrow * 1024 + 64 + lgrp * 16)) ^ xorm; // ks odd

    float cv[4][4];
#pragma unroll
    for (int r = 0; r < 4; ++r)
#pragma unroll
        for (int i = 0; i < 4; ++i)
            cv[r][i] = cov[b * N_SZ + n0 + 16 * r + lgrp * 4 + i];

    const int wslot = ghalf * 8 + wave;            // 64-g block index 0..15
    const short* bbase = wv_pk + (size_t)wslot * 65536 + lane * 8;

    f32x4 acc[4][4];
#pragma unroll
    for (int r = 0; r < 4; ++r)
#pragma unroll
        for (int t = 0; t < 4; ++t) acc[r][t] = (f32x4){0.f, 0.f, 0.f, 0.f};

    // B ping buffer (flat-k ping/pong, continuous across the two chunks)
    bf16x8 bc[4];
#pragma unroll
    for (int t = 0; t < 4; ++t)
        bc[t] = *(const bf16x8*)(bbase + t * 512);

#pragma unroll 1
    for (int c = 0; c < 2; ++c) {
        if (c == 1) {
            __syncthreads();                        // k-loop c0 done reading
            STAGE_CHUNK(512)
            __syncthreads();
        }
#pragma unroll 2
        for (int ks = 0; ks < 16; ++ks) {
            const int kf = c * 16 + ks;
            // prefetch next flat-k B fragments (wrap at end: harmless reload)
            bf16x8 bn[4];
            const int kn = (kf + 1) & 31;
#pragma unroll
            for (int t = 0; t < 4; ++t)
                bn[t] = *(const bf16x8*)(bbase + kn * 2048 + t * 512);

            bf16x8 afr[4];
            const unsigned P = ((ks & 1) ? base_o : base_e) + (unsigned)((ks >> 1) * 128);
#pragma unroll
            for (int r = 0; r < 4; ++r)
                afr[r] = *(const bf16x8*)(smem + P + (unsigned)(r * 16384));
#pragma unroll
            for (int r = 0; r < 4; ++r)
#pragma unroll
                for (int t = 0; t < 4; ++t)
                    acc[r][t] = __builtin_amdgcn_mfma_f32_16x16x32_bf16(
                        afr[r], bc[t], acc[r][t], 0, 0, 0);
#pragma unroll
            for (int t = 0; t < 4; ++t) bc[t] = bn[t];
        }
    }
#undef STAGE_CHUNK

    // epilogue: a = acc + qh + cov*Wc ; e_part += tanh(a)*Wm
    const int gbase = ghalf * 512 + wave * 64;
    float s_part[4][4];
#pragma unroll
    for (int r = 0; r < 4; ++r)
#pragma unroll
        for (int i = 0; i < 4; ++i) s_part[r][i] = 0.f;

#pragma unroll
    for (int t = 0; t < 4; ++t) {
        int g = gbase + 16 * t + lrow;
        float qv = qh[b * 1024 + g];
        float wc = Wc[g];
        float wm = Wm[g];
#pragma unroll
        for (int r = 0; r < 4; ++r)
#pragma unroll
            for (int i = 0; i < 4; ++i) {
                float aval = acc[r][t][i] + qv + cv[r][i] * wc;
                s_part[r][i] += fast_tanh(aval) * wm;
            }
    }

    // reduce across the 16 lanes sharing a row, then accumulate into LDS
#pragma unroll
    for (int r = 0; r < 4; ++r)
#pragma unroll
        for (int i = 0; i < 4; ++i) {
            float s = s_part[r][i];
            s += __shfl_xor(s, 1);
            s += __shfl_xor(s, 2);
            s += __shfl_xor(s, 4);
            s += __shfl_xor(s, 8);
            if (lrow == 0) atomicAdd(&e_sm[16 * r + lgrp * 4 + i], s);
        }
    __syncthreads();
    if (tid < 64)
        e_part[((size_t)ghalf * B_SZ + b) * N_SZ + n0 + tid] = e_sm[tid];
}

// ---------------- kernel 4: mask + softmax over n (sums the two e-halves) ----------------
__global__ __launch_bounds__(256) void softmax_kernel(const float* __restrict__ e_part,
                                                      const int* __restrict__ mask,
                                                      const float* __restrict__ bm,
                                                      float* __restrict__ attn_out) {
    int b = blockIdx.x;
    int t = threadIdx.x;
    int wave = t >> 6, lane = t & 63;
    float bmv = bm[0];
    float vals[8];
    float mx = -1e30f;
#pragma unroll
    for (int j = 0; j < 8; ++j) {
        int n = t + 256 * j;
        float ev = e_part[(size_t)b * N_SZ + n]
                 + e_part[((size_t)B_SZ + b) * N_SZ + n] + bmv;
        if (mask[b * N_SZ + n] <= 0) ev = -1e9f;
        vals[j] = ev;
        mx = fmaxf(mx, ev);
    }
#pragma unroll
    for (int m = 1; m < 64; m <<= 1) mx = fmaxf(mx, __shfl_xor(mx, m));
    __shared__ float redmax[4], redsum[4];
    if (lane == 0) redmax[wave] = mx;
    __syncthreads();
    mx = fmaxf(fmaxf(redmax[0], redmax[1]), fmaxf(redmax[2], redmax[3]));
    float sum = 0.f;
#pragma unroll
    for (int j = 0; j < 8; ++j) {
        vals[j] = expf(vals[j] - mx);
        sum += vals[j];
    }
#pragma unroll
    for (int m = 1; m < 64; m <<= 1) sum += __shfl_xor(sum, m);
    if (lane == 0) redsum[wave] = sum;
    __syncthreads();
    sum = redsum[0] + redsum[1] + redsum[2] + redsum[3];
    float inv = 1.f / sum;
#pragma unroll
    for (int j = 0; j < 8; ++j)
        attn_out[b * N_SZ + t + 256 * j] = vals[j] * inv;
}

// ---------------- kernel 5: partial weighted value sum (16 chunks/batch) ----------------
__global__ __launch_bounds__(256) void wsum_partial_kernel(const float* __restrict__ attn,
                                                           const float* __restrict__ value,
                                                           float* __restrict__ partial) {
    int b = blockIdx.x >> 4;
    int c = blockIdx.x & 15;
    int t = threadIdx.x;
    float4 acc = {0.f, 0.f, 0.f, 0.f};
    const float* vbase = value + (size_t)(b * N_SZ + c * 128) * H_SZ;
    const float* abase = attn + b * N_SZ + c * 128;
    for (int n = 0; n < 128; ++n) {
        float a = abase[n];
        if (a != 0.f) {
            float4 v = *(const float4*)(vbase + (size_t)n * H_SZ + t * 4);
            acc.x += a * v.x; acc.y += a * v.y;
            acc.z += a * v.z; acc.w += a * v.w;
        }
    }
    *(float4*)(partial + (size_t)blockIdx.x * H_SZ + t * 4) = acc;
}

// ---------------- kernel 6: reduce partials -> output ----------------
__global__ __launch_bounds__(256) void wsum_reduce_kernel(const float* __restrict__ partial,
                                                          float* __restrict__ out) {
    int i = blockIdx.x * 256 + threadIdx.x;   // 32768 total
    int b = i >> 10;
    int h = i & 1023;
    float s = 0.f;
#pragma unroll
    for (int c = 0; c < 16; ++c) s += partial[(size_t)(b * 16 + c) * H_SZ + h];
    out[i] = s;
}

extern "C" void kernel_launch(void* const* d_in, const int* in_sizes, int n_in,
                              void* d_out, int out_size, void* d_ws, size_t ws_size,
                              hipStream_t stream) {
    const float* query = (const float*)d_in[0];
    const float* value = (const float*)d_in[1];
    const int*   mask  = (const int*)  d_in[2];
    const float* cov   = (const float*)d_in[3];
    const float* Wq    = (const float*)d_in[4];
    const float* Wv    = (const float*)d_in[5];
    const float* Wc    = (const float*)d_in[6];
    const float* bias  = (const float*)d_in[7];
    const float* Wm    = (const float*)d_in[8];
    const float* bm    = (const float*)d_in[9];

    float* out      = (float*)d_out;            // [32*1024] output
    float* attn_out = out + B_SZ * H_SZ;        // [32*2048] attn

    char* ws = (char*)d_ws;
    short* wv_pk   = (short*)ws;                                       // 2 MB
    float* qh      = (float*)(ws + 2 * 1024 * 1024);                   // 128 KB
    float* e_part  = (float*)(ws + 2 * 1024 * 1024 + 128 * 1024);      // 512 KB (2 halves)
    float* partial = (float*)(ws + 2 * 1024 * 1024 + 640 * 1024);      // 2 MB

    pack_wv_kernel<<<512, 256, 0, stream>>>(Wv, wv_pk);
    qhid_kernel<<<256, 256, 0, stream>>>(query, Wq, bias, qh);

    size_t smem = 65536 + 256;
    fused_score_kernel<<<2048, 512, smem, stream>>>(value, cov, wv_pk, qh, Wc, Wm, e_part);

    softmax_kernel<<<B_SZ, 256, 0, stream>>>(e_part, mask, bm, attn_out);
    wsum_partial_kernel<<<B_SZ * 16, 256, 0, stream>>>(attn_out, value, partial);
    wsum_reduce_kernel<<<128, 256, 0, stream>>>(partial, out);
}

// Round 18
// 190.691 us; speedup vs baseline: 1.3836x; 1.1981x over previous
//
#include <hip/hip_runtime.h>
#include <hip/hip_bf16.h>

#define B_SZ 32
#define N_SZ 2048
#define H_SZ 1024

typedef float f32x4 __attribute__((ext_vector_type(4)));
typedef short bf16x8 __attribute__((ext_vector_type(8)));

static __device__ __forceinline__ unsigned short f2bf(float f) {
    union { float f; unsigned u; } x; x.f = f;
    unsigned r = x.u + 0x7FFF + ((x.u >> 16) & 1);
    return (unsigned short)(r >> 16);
}

// fast tanh: (e^{2x}-1)/(e^{2x}+1), clamped so e never overflows
static __device__ __forceinline__ float fast_tanh(float x) {
    x = fminf(fmaxf(x, -15.f), 15.f);
    float e = __expf(2.f * x);
    return (e - 1.f) / (e + 1.f);
}

// ---------------- kernel 0: mask compaction ----------------
// one block per batch; idx[b][j] = n of j-th active row (ascending), count[b].
__global__ __launch_bounds__(256) void compact_kernel(const int* __restrict__ mask,
                                                      int* __restrict__ idx,
                                                      int* __restrict__ count) {
    int b = blockIdx.x;
    int t = threadIdx.x;
    const int* m = mask + b * N_SZ + t * 8;
    int c = 0;
#pragma unroll
    for (int i = 0; i < 8; ++i) c += (m[i] > 0);
    __shared__ int sc[256];
    sc[t] = c;
    __syncthreads();
    // Hillis-Steele inclusive scan over 256 entries
    for (int off = 1; off < 256; off <<= 1) {
        int v = (t >= off) ? sc[t - off] : 0;
        __syncthreads();
        sc[t] += v;
        __syncthreads();
    }
    int base = sc[t] - c;            // exclusive prefix
#pragma unroll
    for (int i = 0; i < 8; ++i) {
        if (m[i] > 0) {
            idx[b * N_SZ + base] = t * 8 + i;
            ++base;
        }
    }
    if (t == 255) count[b] = sc[255];
}

// ---------------- kernel 1: pack Wv f32 -> bf16 in wave-fragment order ----------------
// packed element index: ((((w*32 + k)*4 + t)*64) + lane)*8 + j
//   maps to Wv[g][h], g = w*64 + 16t + (lane&15), h = k*32 + (lane>>4)*8 + j
__global__ __launch_bounds__(256) void pack_wv_kernel(const float* __restrict__ wv,
                                                      short* __restrict__ out) {
    int o8 = blockIdx.x * 256 + threadIdx.x;      // 131072 threads, 8 elems each
    int lane = o8 & 63;
    int t    = (o8 >> 6) & 3;
    int k    = (o8 >> 8) & 31;
    int w    = (o8 >> 13) & 15;
    int g  = w * 64 + 16 * t + (lane & 15);
    int h0 = k * 32 + (lane >> 4) * 8;
    const float* src = wv + (size_t)g * 1024 + h0;
    float4 v0 = *(const float4*)(src);
    float4 v1 = *(const float4*)(src + 4);
    short4 s0, s1;
    s0.x = (short)f2bf(v0.x); s0.y = (short)f2bf(v0.y);
    s0.z = (short)f2bf(v0.z); s0.w = (short)f2bf(v0.w);
    s1.x = (short)f2bf(v1.x); s1.y = (short)f2bf(v1.y);
    s1.z = (short)f2bf(v1.z); s1.w = (short)f2bf(v1.w);
    *(short4*)(out + (size_t)o8 * 8)     = s0;
    *(short4*)(out + (size_t)o8 * 8 + 4) = s1;
}

// ---------------- kernel 2: q_hid = query @ Wq.T + bias ----------------
__global__ __launch_bounds__(256) void qhid_kernel(const float* __restrict__ query,
                                                   const float* __restrict__ Wq,
                                                   const float* __restrict__ bias,
                                                   float* __restrict__ qh) {
    int gb = blockIdx.x * 4;
    __shared__ float wsm[4][1024];
    int t = threadIdx.x;
    for (int i = t; i < 4096; i += 256)
        wsm[i >> 10][i & 1023] = Wq[(size_t)gb * 1024 + i];
    __syncthreads();
    int gi = t >> 6;
    int lane = t & 63;
    int b = lane >> 1;
    int half = lane & 1;
    const float4* q = (const float4*)(query + b * 1024 + half * 512);
    const float4* w = (const float4*)(&wsm[gi][half * 512]);
    float acc = 0.f;
#pragma unroll 8
    for (int h = 0; h < 128; ++h) {
        float4 qv = q[h]; float4 wv = w[h];
        acc += qv.x * wv.x + qv.y * wv.y + qv.z * wv.z + qv.w * wv.w;
    }
    acc += __shfl_xor(acc, 1);
    if (half == 0) qh[b * 1024 + gb + gi] = acc + bias[gb + gi];
}

// ---------------- kernel 3: fused score GEMM + tanh + Wm dot (compacted) ----------------
// r15 structure (512 threads, 8 waves, 64KB LDS, 2 blocks/CU, XCD-paired
// siblings) over COMPACTED rows: block = one 64-row panel of the ~count[b]
// active rows x one 512-g half. Blocks past count[b] exit immediately (~half).
// Rows gathered via idx (4KB-contiguous rows -> coalescing preserved; both
// siblings gather the same rows -> L2 sharing preserved). e scattered back
// through idx; masked e entries never written (softmax substitutes -1e9).
__global__ __launch_bounds__(512, 4) void fused_score_kernel(
    const float* __restrict__ value, const float* __restrict__ cov,
    const short* __restrict__ wv_pk, const float* __restrict__ qh,
    const float* __restrict__ Wc, const float* __restrict__ Wm,
    const int* __restrict__ idx, const int* __restrict__ count,
    float* __restrict__ e_part)
{
    extern __shared__ char smem[];                 // 64KB A-chunk + e_sm
    float* e_sm = (float*)(smem + 65536);

    const int wgid  = blockIdx.x;
    const int p     = ((wgid >> 4) << 3) | (wgid & 7);   // panel 0..1023
    const int ghalf = (wgid >> 3) & 1;                   // which 512-g half
    const int b     = p >> 5;
    const int n0    = (p & 31) * 64;                     // panel start in COMPACTED space
    const int tid   = threadIdx.x;

    const int cnt = count[b];
    if (n0 >= cnt) return;                         // uniform early exit

    if (tid < 64) e_sm[tid] = 0.f;

    const int* bidx = idx + b * N_SZ;

    // staging role: lanes 0-7 share a row (128B contiguous global segments)
    const int srow  = tid >> 3;                    // 0..63
    const int scol8 = tid & 7;                     // 0..7 (8 f32 each)
    const int jrow  = n0 + srow;                   // compacted row id
    const int gn    = (jrow < cnt) ? bidx[jrow] : 0;   // gathered n (pad -> row 0)
    const float* gsrc = value + ((size_t)b * N_SZ + gn) * H_SZ + scol8 * 8;
    const unsigned wswz = (unsigned)((srow & 7) << 4);
    const unsigned wbase = (unsigned)(srow * 1024 + scol8 * 16);

#define STAGE_CHUNK(CB)                                                        \
    {                                                                          \
        _Pragma("unroll")                                                      \
        for (int it = 0; it < 8; ++it) {                                       \
            float4 q0 = *(const float4*)(gsrc + (CB) + it * 64);               \
            float4 q1 = *(const float4*)(gsrc + (CB) + it * 64 + 4);           \
            bf16x8 w;                                                          \
            w[0] = (short)f2bf(q0.x); w[1] = (short)f2bf(q0.y);                \
            w[2] = (short)f2bf(q0.z); w[3] = (short)f2bf(q0.w);                \
            w[4] = (short)f2bf(q1.x); w[5] = (short)f2bf(q1.y);                \
            w[6] = (short)f2bf(q1.z); w[7] = (short)f2bf(q1.w);                \
            *(bf16x8*)(smem + ((wbase + (unsigned)(it * 128)) ^ wswz)) = w;    \
        }                                                                      \
    }

    // ---- stage chunk 0 (cols 0-511) ----
    STAGE_CHUNK(0)
    __syncthreads();

    const int wave = tid >> 6;
    const int lane = tid & 63;
    const int lrow = lane & 15;
    const int lgrp = lane >> 4;
    const unsigned xorm = (unsigned)((lrow & 7) << 4);
    // chunk-local swizzled bases (row stride 1024B), ks-parity split
    const unsigned base_e = ((unsigned)(lrow * 1024 + lgrp * 16)) ^ xorm;      // ks even
    const unsigned base_o = ((unsigned)(lrow * 1024 + 64 + lgrp * 16)) ^ xorm; // ks odd

    // cov gathered through idx for the 16 rows this lane touches
    float cv[4][4];
#pragma unroll
    for (int r = 0; r < 4; ++r)
#pragma unroll
        for (int i = 0; i < 4; ++i) {
            int jr = n0 + 16 * r + lgrp * 4 + i;
            int gnn = (jr < cnt) ? bidx[jr] : 0;
            cv[r][i] = cov[b * N_SZ + gnn];
        }

    const int wslot = ghalf * 8 + wave;            // 64-g block index 0..15
    const short* bbase = wv_pk + (size_t)wslot * 65536 + lane * 8;

    f32x4 acc[4][4];
#pragma unroll
    for (int r = 0; r < 4; ++r)
#pragma unroll
        for (int t = 0; t < 4; ++t) acc[r][t] = (f32x4){0.f, 0.f, 0.f, 0.f};

    // B ping buffer (flat-k ping/pong, continuous across the two chunks)
    bf16x8 bc[4];
#pragma unroll
    for (int t = 0; t < 4; ++t)
        bc[t] = *(const bf16x8*)(bbase + t * 512);

#pragma unroll 1
    for (int c = 0; c < 2; ++c) {
        if (c == 1) {
            __syncthreads();                        // k-loop c0 done reading
            STAGE_CHUNK(512)
            __syncthreads();
        }
#pragma unroll 2
        for (int ks = 0; ks < 16; ++ks) {
            const int kf = c * 16 + ks;
            // prefetch next flat-k B fragments (wrap at end: harmless reload)
            bf16x8 bn[4];
            const int kn = (kf + 1) & 31;
#pragma unroll
            for (int t = 0; t < 4; ++t)
                bn[t] = *(const bf16x8*)(bbase + kn * 2048 + t * 512);

            bf16x8 afr[4];
            const unsigned P = ((ks & 1) ? base_o : base_e) + (unsigned)((ks >> 1) * 128);
#pragma unroll
            for (int r = 0; r < 4; ++r)
                afr[r] = *(const bf16x8*)(smem + P + (unsigned)(r * 16384));
#pragma unroll
            for (int r = 0; r < 4; ++r)
#pragma unroll
                for (int t = 0; t < 4; ++t)
                    acc[r][t] = __builtin_amdgcn_mfma_f32_16x16x32_bf16(
                        afr[r], bc[t], acc[r][t], 0, 0, 0);
#pragma unroll
            for (int t = 0; t < 4; ++t) bc[t] = bn[t];
        }
    }
#undef STAGE_CHUNK

    // epilogue: a = acc + qh + cov*Wc ; e_part += tanh(a)*Wm
    const int gbase = ghalf * 512 + wave * 64;
    float s_part[4][4];
#pragma unroll
    for (int r = 0; r < 4; ++r)
#pragma unroll
        for (int i = 0; i < 4; ++i) s_part[r][i] = 0.f;

#pragma unroll
    for (int t = 0; t < 4; ++t) {
        int g = gbase + 16 * t + lrow;
        float qv = qh[b * 1024 + g];
        float wc = Wc[g];
        float wm = Wm[g];
#pragma unroll
        for (int r = 0; r < 4; ++r)
#pragma unroll
            for (int i = 0; i < 4; ++i) {
                float aval = acc[r][t][i] + qv + cv[r][i] * wc;
                s_part[r][i] += fast_tanh(aval) * wm;
            }
    }

    // reduce across the 16 lanes sharing a row, then accumulate into LDS
#pragma unroll
    for (int r = 0; r < 4; ++r)
#pragma unroll
        for (int i = 0; i < 4; ++i) {
            float s = s_part[r][i];
            s += __shfl_xor(s, 1);
            s += __shfl_xor(s, 2);
            s += __shfl_xor(s, 4);
            s += __shfl_xor(s, 8);
            if (lrow == 0) atomicAdd(&e_sm[16 * r + lgrp * 4 + i], s);
        }
    __syncthreads();
    // scatter back to original n positions; padded rows skipped
    if (tid < 64 && n0 + tid < cnt)
        e_part[((size_t)ghalf * B_SZ + b) * N_SZ + bidx[n0 + tid]] = e_sm[tid];
}

// ---------------- kernel 4: mask + softmax over n (sums the two e-halves) ----------------
__global__ __launch_bounds__(256) void softmax_kernel(const float* __restrict__ e_part,
                                                      const int* __restrict__ mask,
                                                      const float* __restrict__ bm,
                                                      float* __restrict__ attn_out) {
    int b = blockIdx.x;
    int t = threadIdx.x;
    int wave = t >> 6, lane = t & 63;
    float bmv = bm[0];
    float vals[8];
    float mx = -1e30f;
#pragma unroll
    for (int j = 0; j < 8; ++j) {
        int n = t + 256 * j;
        float ev = e_part[(size_t)b * N_SZ + n]
                 + e_part[((size_t)B_SZ + b) * N_SZ + n] + bmv;
        if (mask[b * N_SZ + n] <= 0) ev = -1e9f;   // masked entries never computed
        vals[j] = ev;
        mx = fmaxf(mx, ev);
    }
#pragma unroll
    for (int m = 1; m < 64; m <<= 1) mx = fmaxf(mx, __shfl_xor(mx, m));
    __shared__ float redmax[4], redsum[4];
    if (lane == 0) redmax[wave] = mx;
    __syncthreads();
    mx = fmaxf(fmaxf(redmax[0], redmax[1]), fmaxf(redmax[2], redmax[3]));
    float sum = 0.f;
#pragma unroll
    for (int j = 0; j < 8; ++j) {
        vals[j] = expf(vals[j] - mx);
        sum += vals[j];
    }
#pragma unroll
    for (int m = 1; m < 64; m <<= 1) sum += __shfl_xor(sum, m);
    if (lane == 0) redsum[wave] = sum;
    __syncthreads();
    sum = redsum[0] + redsum[1] + redsum[2] + redsum[3];
    float inv = 1.f / sum;
#pragma unroll
    for (int j = 0; j < 8; ++j)
        attn_out[b * N_SZ + t + 256 * j] = vals[j] * inv;
}

// ---------------- kernel 5: partial weighted value sum (16 chunks/batch) ----------------
__global__ __launch_bounds__(256) void wsum_partial_kernel(const float* __restrict__ attn,
                                                           const float* __restrict__ value,
                                                           float* __restrict__ partial) {
    int b = blockIdx.x >> 4;
    int c = blockIdx.x & 15;
    int t = threadIdx.x;
    float4 acc = {0.f, 0.f, 0.f, 0.f};
    const float* vbase = value + (size_t)(b * N_SZ + c * 128) * H_SZ;
    const float* abase = attn + b * N_SZ + c * 128;
    for (int n = 0; n < 128; ++n) {
        float a = abase[n];
        if (a != 0.f) {
            float4 v = *(const float4*)(vbase + (size_t)n * H_SZ + t * 4);
            acc.x += a * v.x; acc.y += a * v.y;
            acc.z += a * v.z; acc.w += a * v.w;
        }
    }
    *(float4*)(partial + (size_t)blockIdx.x * H_SZ + t * 4) = acc;
}

// ---------------- kernel 6: reduce partials -> output ----------------
__global__ __launch_bounds__(256) void wsum_reduce_kernel(const float* __restrict__ partial,
                                                          float* __restrict__ out) {
    int i = blockIdx.x * 256 + threadIdx.x;   // 32768 total
    int b = i >> 10;
    int h = i & 1023;
    float s = 0.f;
#pragma unroll
    for (int c = 0; c < 16; ++c) s += partial[(size_t)(b * 16 + c) * H_SZ + h];
    out[i] = s;
}

extern "C" void kernel_launch(void* const* d_in, const int* in_sizes, int n_in,
                              void* d_out, int out_size, void* d_ws, size_t ws_size,
                              hipStream_t stream) {
    const float* query = (const float*)d_in[0];
    const float* value = (const float*)d_in[1];
    const int*   mask  = (const int*)  d_in[2];
    const float* cov   = (const float*)d_in[3];
    const float* Wq    = (const float*)d_in[4];
    const float* Wv    = (const float*)d_in[5];
    const float* Wc    = (const float*)d_in[6];
    const float* bias  = (const float*)d_in[7];
    const float* Wm    = (const float*)d_in[8];
    const float* bm    = (const float*)d_in[9];

    float* out      = (float*)d_out;            // [32*1024] output
    float* attn_out = out + B_SZ * H_SZ;        // [32*2048] attn

    char* ws = (char*)d_ws;
    short* wv_pk   = (short*)ws;                                        // 2 MB
    float* qh      = (float*)(ws + 2 * 1024 * 1024);                    // 128 KB
    float* e_part  = (float*)(ws + 2 * 1024 * 1024 + 128 * 1024);       // 512 KB (2 halves)
    float* partial = (float*)(ws + 2 * 1024 * 1024 + 640 * 1024);       // 2 MB
    int*   idx     = (int*)  (ws + 4 * 1024 * 1024 + 640 * 1024);       // 256 KB
    int*   count   = (int*)  (ws + 4 * 1024 * 1024 + 896 * 1024);       // 128 B

    compact_kernel<<<B_SZ, 256, 0, stream>>>(mask, idx, count);
    pack_wv_kernel<<<512, 256, 0, stream>>>(Wv, wv_pk);
    qhid_kernel<<<256, 256, 0, stream>>>(query, Wq, bias, qh);

    size_t smem = 65536 + 256;
    fused_score_kernel<<<2048, 512, smem, stream>>>(value, cov, wv_pk, qh, Wc, Wm,
                                                    idx, count, e_part);

    softmax_kernel<<<B_SZ, 256, 0, stream>>>(e_part, mask, bm, attn_out);
    wsum_partial_kernel<<<B_SZ * 16, 256, 0, stream>>>(attn_out, value, partial);
    wsum_reduce_kernel<<<128, 256, 0, stream>>>(partial, out);
}

// Round 20
// 168.082 us; speedup vs baseline: 1.5697x; 1.1345x over previous
//
#include <hip/hip_runtime.h>
#include <hip/hip_bf16.h>

#define B_SZ 32
#define N_SZ 2048
#define H_SZ 1024

typedef float f32x4 __attribute__((ext_vector_type(4)));
typedef short bf16x8 __attribute__((ext_vector_type(8)));

static __device__ __forceinline__ unsigned short f2bf(float f) {
    union { float f; unsigned u; } x; x.f = f;
    unsigned r = x.u + 0x7FFF + ((x.u >> 16) & 1);
    return (unsigned short)(r >> 16);
}

// fast tanh: (e^{2x}-1)/(e^{2x}+1), clamped so e never overflows
static __device__ __forceinline__ float fast_tanh(float x) {
    x = fminf(fmaxf(x, -15.f), 15.f);
    float e = __expf(2.f * x);
    return (e - 1.f) / (e + 1.f);
}

// ---------------- kernel 0: mask compaction ----------------
// one block per batch; idx[b][j] = n of j-th active row (ascending), count[b].
__global__ __launch_bounds__(256) void compact_kernel(const int* __restrict__ mask,
                                                      int* __restrict__ idx,
                                                      int* __restrict__ count) {
    int b = blockIdx.x;
    int t = threadIdx.x;
    const int* m = mask + b * N_SZ + t * 8;
    int c = 0;
#pragma unroll
    for (int i = 0; i < 8; ++i) c += (m[i] > 0);
    __shared__ int sc[256];
    sc[t] = c;
    __syncthreads();
    // Hillis-Steele inclusive scan over 256 entries
    for (int off = 1; off < 256; off <<= 1) {
        int v = (t >= off) ? sc[t - off] : 0;
        __syncthreads();
        sc[t] += v;
        __syncthreads();
    }
    int base = sc[t] - c;            // exclusive prefix
#pragma unroll
    for (int i = 0; i < 8; ++i) {
        if (m[i] > 0) {
            idx[b * N_SZ + base] = t * 8 + i;
            ++base;
        }
    }
    if (t == 255) count[b] = sc[255];
}

// ---------------- kernel 1: pack Wv f32 -> bf16 in wave-fragment order ----------------
// packed element index: ((((w*32 + k)*4 + t)*64) + lane)*8 + j
//   maps to Wv[g][h], g = w*64 + 16t + (lane&15), h = k*32 + (lane>>4)*8 + j
__global__ __launch_bounds__(256) void pack_wv_kernel(const float* __restrict__ wv,
                                                      short* __restrict__ out) {
    int o8 = blockIdx.x * 256 + threadIdx.x;      // 131072 threads, 8 elems each
    int lane = o8 & 63;
    int t    = (o8 >> 6) & 3;
    int k    = (o8 >> 8) & 31;
    int w    = (o8 >> 13) & 15;
    int g  = w * 64 + 16 * t + (lane & 15);
    int h0 = k * 32 + (lane >> 4) * 8;
    const float* src = wv + (size_t)g * 1024 + h0;
    float4 v0 = *(const float4*)(src);
    float4 v1 = *(const float4*)(src + 4);
    short4 s0, s1;
    s0.x = (short)f2bf(v0.x); s0.y = (short)f2bf(v0.y);
    s0.z = (short)f2bf(v0.z); s0.w = (short)f2bf(v0.w);
    s1.x = (short)f2bf(v1.x); s1.y = (short)f2bf(v1.y);
    s1.z = (short)f2bf(v1.z); s1.w = (short)f2bf(v1.w);
    *(short4*)(out + (size_t)o8 * 8)     = s0;
    *(short4*)(out + (size_t)o8 * 8 + 4) = s1;
}

// ---------------- kernel 2: q_hid = query @ Wq.T + bias ----------------
__global__ __launch_bounds__(256) void qhid_kernel(const float* __restrict__ query,
                                                   const float* __restrict__ Wq,
                                                   const float* __restrict__ bias,
                                                   float* __restrict__ qh) {
    int gb = blockIdx.x * 4;
    __shared__ float wsm[4][1024];
    int t = threadIdx.x;
    for (int i = t; i < 4096; i += 256)
        wsm[i >> 10][i & 1023] = Wq[(size_t)gb * 1024 + i];
    __syncthreads();
    int gi = t >> 6;
    int lane = t & 63;
    int b = lane >> 1;
    int half = lane & 1;
    const float4* q = (const float4*)(query + b * 1024 + half * 512);
    const float4* w = (const float4*)(&wsm[gi][half * 512]);
    float acc = 0.f;
#pragma unroll 8
    for (int h = 0; h < 128; ++h) {
        float4 qv = q[h]; float4 wv = w[h];
        acc += qv.x * wv.x + qv.y * wv.y + qv.z * wv.z + qv.w * wv.w;
    }
    acc += __shfl_xor(acc, 1);
    if (half == 0) qh[b * 1024 + gb + gi] = acc + bias[gb + gi];
}

// ---------------- kernel 3: fused score GEMM + tanh + Wm dot (compacted) ----------------
// r18 kernel with PANEL-MAJOR block decode: q = global panel index with b FAST
// (b = q&31, panel = q>>5). Since np[b] = ceil(cnt/64) ~ 16+-1 for ALL batches,
// live blocks (panel < np[b]) are contiguous at the FRONT of dispatch order and
// dead blocks retire in one burst at the tail -> dense CU packing without any
// job-list indirection (r19's joblist failed post-timing revalidation).
// Siblings (same q, ghalf 0/1) remain 8 apart in blockIdx -> same XCD -> the
// panel's 2nd HBM read stays an L2 hit (r15-verified).
__global__ __launch_bounds__(512, 4) void fused_score_kernel(
    const float* __restrict__ value, const float* __restrict__ cov,
    const short* __restrict__ wv_pk, const float* __restrict__ qh,
    const float* __restrict__ Wc, const float* __restrict__ Wm,
    const int* __restrict__ idx, const int* __restrict__ count,
    float* __restrict__ e_part)
{
    extern __shared__ char smem[];                 // 64KB A-chunk + e_sm
    float* e_sm = (float*)(smem + 65536);

    const int wgid  = blockIdx.x;
    const int q     = ((wgid >> 4) << 3) | (wgid & 7);   // global panel 0..1023, b-fast
    const int ghalf = (wgid >> 3) & 1;                   // which 512-g half
    const int b     = q & 31;
    const int panel = q >> 5;
    const int n0    = panel * 64;                  // panel start in COMPACTED space
    const int tid   = threadIdx.x;

    const int cnt = count[b];
    if (n0 >= cnt) return;                         // dead blocks: tail of dispatch

    if (tid < 64) e_sm[tid] = 0.f;

    const int* bidx = idx + b * N_SZ;

    // staging role: lanes 0-7 share a row (128B contiguous global segments)
    const int srow  = tid >> 3;                    // 0..63
    const int scol8 = tid & 7;                     // 0..7 (8 f32 each)
    const int jrow  = n0 + srow;                   // compacted row id
    const int gn    = (jrow < cnt) ? bidx[jrow] : 0;   // gathered n (pad -> row 0)
    const float* gsrc = value + ((size_t)b * N_SZ + gn) * H_SZ + scol8 * 8;
    const unsigned wswz = (unsigned)((srow & 7) << 4);
    const unsigned wbase = (unsigned)(srow * 1024 + scol8 * 16);

#define STAGE_CHUNK(CB)                                                        \
    {                                                                          \
        _Pragma("unroll")                                                      \
        for (int it = 0; it < 8; ++it) {                                       \
            float4 q0 = *(const float4*)(gsrc + (CB) + it * 64);               \
            float4 q1 = *(const float4*)(gsrc + (CB) + it * 64 + 4);           \
            bf16x8 w;                                                          \
            w[0] = (short)f2bf(q0.x); w[1] = (short)f2bf(q0.y);                \
            w[2] = (short)f2bf(q0.z); w[3] = (short)f2bf(q0.w);                \
            w[4] = (short)f2bf(q1.x); w[5] = (short)f2bf(q1.y);                \
            w[6] = (short)f2bf(q1.z); w[7] = (short)f2bf(q1.w);                \
            *(bf16x8*)(smem + ((wbase + (unsigned)(it * 128)) ^ wswz)) = w;    \
        }                                                                      \
    }

    // ---- stage chunk 0 (cols 0-511) ----
    STAGE_CHUNK(0)
    __syncthreads();

    const int wave = tid >> 6;
    const int lane = tid & 63;
    const int lrow = lane & 15;
    const int lgrp = lane >> 4;
    const unsigned xorm = (unsigned)((lrow & 7) << 4);
    // chunk-local swizzled bases (row stride 1024B), ks-parity split
    const unsigned base_e = ((unsigned)(lrow * 1024 + lgrp * 16)) ^ xorm;      // ks even
    const unsigned base_o = ((unsigned)(lrow * 1024 + 64 + lgrp * 16)) ^ xorm; // ks odd

    // cov gathered through idx for the 16 rows this lane touches
    float cv[4][4];
#pragma unroll
    for (int r = 0; r < 4; ++r)
#pragma unroll
        for (int i = 0; i < 4; ++i) {
            int jr = n0 + 16 * r + lgrp * 4 + i;
            int gnn = (jr < cnt) ? bidx[jr] : 0;
            cv[r][i] = cov[b * N_SZ + gnn];
        }

    const int wslot = ghalf * 8 + wave;            // 64-g block index 0..15
    const short* bbase = wv_pk + (size_t)wslot * 65536 + lane * 8;

    f32x4 acc[4][4];
#pragma unroll
    for (int r = 0; r < 4; ++r)
#pragma unroll
        for (int t = 0; t < 4; ++t) acc[r][t] = (f32x4){0.f, 0.f, 0.f, 0.f};

    // B ping buffer (flat-k ping/pong, continuous across the two chunks)
    bf16x8 bc[4];
#pragma unroll
    for (int t = 0; t < 4; ++t)
        bc[t] = *(const bf16x8*)(bbase + t * 512);

#pragma unroll 1
    for (int c = 0; c < 2; ++c) {
        if (c == 1) {
            __syncthreads();                        // k-loop c0 done reading
            STAGE_CHUNK(512)
            __syncthreads();
        }
#pragma unroll 2
        for (int ks = 0; ks < 16; ++ks) {
            const int kf = c * 16 + ks;
            // prefetch next flat-k B fragments (wrap at end: harmless reload)
            bf16x8 bn[4];
            const int kn = (kf + 1) & 31;
#pragma unroll
            for (int t = 0; t < 4; ++t)
                bn[t] = *(const bf16x8*)(bbase + kn * 2048 + t * 512);

            bf16x8 afr[4];
            const unsigned P = ((ks & 1) ? base_o : base_e) + (unsigned)((ks >> 1) * 128);
#pragma unroll
            for (int r = 0; r < 4; ++r)
                afr[r] = *(const bf16x8*)(smem + P + (unsigned)(r * 16384));
#pragma unroll
            for (int r = 0; r < 4; ++r)
#pragma unroll
                for (int t = 0; t < 4; ++t)
                    acc[r][t] = __builtin_amdgcn_mfma_f32_16x16x32_bf16(
                        afr[r], bc[t], acc[r][t], 0, 0, 0);
#pragma unroll
            for (int t = 0; t < 4; ++t) bc[t] = bn[t];
        }
    }
#undef STAGE_CHUNK

    // epilogue: a = acc + qh + cov*Wc ; e_part += tanh(a)*Wm
    const int gbase = ghalf * 512 + wave * 64;
    float s_part[4][4];
#pragma unroll
    for (int r = 0; r < 4; ++r)
#pragma unroll
        for (int i = 0; i < 4; ++i) s_part[r][i] = 0.f;

#pragma unroll
    for (int t = 0; t < 4; ++t) {
        int g = gbase + 16 * t + lrow;
        float qv = qh[b * 1024 + g];
        float wc = Wc[g];
        float wm = Wm[g];
#pragma unroll
        for (int r = 0; r < 4; ++r)
#pragma unroll
            for (int i = 0; i < 4; ++i) {
                float aval = acc[r][t][i] + qv + cv[r][i] * wc;
                s_part[r][i] += fast_tanh(aval) * wm;
            }
    }

    // reduce across the 16 lanes sharing a row, then accumulate into LDS
#pragma unroll
    for (int r = 0; r < 4; ++r)
#pragma unroll
        for (int i = 0; i < 4; ++i) {
            float s = s_part[r][i];
            s += __shfl_xor(s, 1);
            s += __shfl_xor(s, 2);
            s += __shfl_xor(s, 4);
            s += __shfl_xor(s, 8);
            if (lrow == 0) atomicAdd(&e_sm[16 * r + lgrp * 4 + i], s);
        }
    __syncthreads();
    // scatter back to original n positions; padded rows skipped
    if (tid < 64 && n0 + tid < cnt)
        e_part[((size_t)ghalf * B_SZ + b) * N_SZ + bidx[n0 + tid]] = e_sm[tid];
}

// ---------------- kernel 4: mask + softmax over n (sums the two e-halves) ----------------
__global__ __launch_bounds__(256) void softmax_kernel(const float* __restrict__ e_part,
                                                      const int* __restrict__ mask,
                                                      const float* __restrict__ bm,
                                                      float* __restrict__ attn_out) {
    int b = blockIdx.x;
    int t = threadIdx.x;
    int wave = t >> 6, lane = t & 63;
    float bmv = bm[0];
    float vals[8];
    float mx = -1e30f;
#pragma unroll
    for (int j = 0; j < 8; ++j) {
        int n = t + 256 * j;
        float ev = e_part[(size_t)b * N_SZ + n]
                 + e_part[((size_t)B_SZ + b) * N_SZ + n] + bmv;
        if (mask[b * N_SZ + n] <= 0) ev = -1e9f;   // masked entries never computed
        vals[j] = ev;
        mx = fmaxf(mx, ev);
    }
#pragma unroll
    for (int m = 1; m < 64; m <<= 1) mx = fmaxf(mx, __shfl_xor(mx, m));
    __shared__ float redmax[4], redsum[4];
    if (lane == 0) redmax[wave] = mx;
    __syncthreads();
    mx = fmaxf(fmaxf(redmax[0], redmax[1]), fmaxf(redmax[2], redmax[3]));
    float sum = 0.f;
#pragma unroll
    for (int j = 0; j < 8; ++j) {
        vals[j] = expf(vals[j] - mx);
        sum += vals[j];
    }
#pragma unroll
    for (int m = 1; m < 64; m <<= 1) sum += __shfl_xor(sum, m);
    if (lane == 0) redsum[wave] = sum;
    __syncthreads();
    sum = redsum[0] + redsum[1] + redsum[2] + redsum[3];
    float inv = 1.f / sum;
#pragma unroll
    for (int j = 0; j < 8; ++j)
        attn_out[b * N_SZ + t + 256 * j] = vals[j] * inv;
}

// ---------------- kernel 5: partial weighted value sum (16 chunks/batch) ----------------
__global__ __launch_bounds__(256) void wsum_partial_kernel(const float* __restrict__ attn,
                                                           const float* __restrict__ value,
                                                           float* __restrict__ partial) {
    int b = blockIdx.x >> 4;
    int c = blockIdx.x & 15;
    int t = threadIdx.x;
    float4 acc = {0.f, 0.f, 0.f, 0.f};
    const float* vbase = value + (size_t)(b * N_SZ + c * 128) * H_SZ;
    const float* abase = attn + b * N_SZ + c * 128;
    for (int n = 0; n < 128; ++n) {
        float a = abase[n];
        if (a != 0.f) {
            float4 v = *(const float4*)(vbase + (size_t)n * H_SZ + t * 4);
            acc.x += a * v.x; acc.y += a * v.y;
            acc.z += a * v.z; acc.w += a * v.w;
        }
    }
    *(float4*)(partial + (size_t)blockIdx.x * H_SZ + t * 4) = acc;
}

// ---------------- kernel 6: reduce partials -> output ----------------
__global__ __launch_bounds__(256) void wsum_reduce_kernel(const float* __restrict__ partial,
                                                          float* __restrict__ out) {
    int i = blockIdx.x * 256 + threadIdx.x;   // 32768 total
    int b = i >> 10;
    int h = i & 1023;
    float s = 0.f;
#pragma unroll
    for (int c = 0; c < 16; ++c) s += partial[(size_t)(b * 16 + c) * H_SZ + h];
    out[i] = s;
}

extern "C" void kernel_launch(void* const* d_in, const int* in_sizes, int n_in,
                              void* d_out, int out_size, void* d_ws, size_t ws_size,
                              hipStream_t stream) {
    const float* query = (const float*)d_in[0];
    const float* value = (const float*)d_in[1];
    const int*   mask  = (const int*)  d_in[2];
    const float* cov   = (const float*)d_in[3];
    const float* Wq    = (const float*)d_in[4];
    const float* Wv    = (const float*)d_in[5];
    const float* Wc    = (const float*)d_in[6];
    const float* bias  = (const float*)d_in[7];
    const float* Wm    = (const float*)d_in[8];
    const float* bm    = (const float*)d_in[9];

    float* out      = (float*)d_out;            // [32*1024] output
    float* attn_out = out + B_SZ * H_SZ;        // [32*2048] attn

    char* ws = (char*)d_ws;
    short* wv_pk   = (short*)ws;                                        // 2 MB
    float* qh      = (float*)(ws + 2 * 1024 * 1024);                    // 128 KB
    float* e_part  = (float*)(ws + 2 * 1024 * 1024 + 128 * 1024);       // 512 KB (2 halves)
    float* partial = (float*)(ws + 2 * 1024 * 1024 + 640 * 1024);       // 2 MB
    int*   idx     = (int*)  (ws + 4 * 1024 * 1024 + 640 * 1024);       // 256 KB
    int*   count   = (int*)  (ws + 4 * 1024 * 1024 + 896 * 1024);       // 128 B

    compact_kernel<<<B_SZ, 256, 0, stream>>>(mask, idx, count);
    pack_wv_kernel<<<512, 256, 0, stream>>>(Wv, wv_pk);
    qhid_kernel<<<256, 256, 0, stream>>>(query, Wq, bias, qh);

    size_t smem = 65536 + 256;
    fused_score_kernel<<<2048, 512, smem, stream>>>(value, cov, wv_pk, qh, Wc, Wm,
                                                    idx, count, e_part);

    softmax_kernel<<<B_SZ, 256, 0, stream>>>(e_part, mask, bm, attn_out);
    wsum_partial_kernel<<<B_SZ * 16, 256, 0, stream>>>(attn_out, value, partial);
    wsum_reduce_kernel<<<128, 256, 0, stream>>>(partial, out);
}